// Round 9
// baseline (205.732 us; speedup 1.0000x reference)
//
#include <hip/hip_runtime.h>
#include <cmath>

typedef unsigned int uint;
typedef unsigned short u16;

constexpr int N  = 131072;    // nodes
constexpr int E  = 4194304;   // edges (without self-loops)
constexpr int F  = 16;        // hidden width H1
constexpr int NB = 512;       // dst buckets of 256 nodes (bucket = dst>>8)
constexpr int NBLK  = 512;    // scatter blocks
constexpr int SCT   = 512;    // threads per scatter/sort block
constexpr int CHUNK = 8192;   // edges per scatter block (NBLK*CHUNK == E)
constexpr int EPT   = 16;     // edges per thread in scatter
constexpr int CAPB  = 9216;   // padded per-bucket region (mean 8192, sd ~90 -> 11 sd)
constexpr int LPN   = 16;     // lanes per node in k_l1/k_l2 (== F)

// ---- Phase A: block-local bucket grouping, private regions, coalesced ------
// Block g: groups its 8192 edges by bucket in LDS, writes them to
// part[g*CHUNK ...] (fully coalesced), and emits a directory:
//   cnt16[b*NBLK+g] = #edges of bucket b in block g
//   dir16[b*NBLK+g] = local offset of bucket b's run inside block g's region
__global__ void __launch_bounds__(SCT) k_scatter(
        const int* __restrict__ src, const int* __restrict__ dst,
        uint* __restrict__ part, u16* __restrict__ cnt16, u16* __restrict__ dir16) {
    __shared__ uint h[NB];          // hist -> bump counters
    __shared__ uint wsum[8];
    __shared__ uint vals[CHUNK];    // 32 KB staging
    int t = threadIdx.x, g = blockIdx.x;
    int lane = t & 63, w = t >> 6;
    h[t] = 0;
    __syncthreads();
    int d[EPT], s[EPT];
    const int4* src4 = (const int4*)src;
    const int4* dst4 = (const int4*)dst;
    int base4 = g * (CHUNK / 4);
#pragma unroll
    for (int k = 0; k < EPT / 4; ++k) {
        int4 d4 = dst4[base4 + k * SCT + t];
        int4 s4 = src4[base4 + k * SCT + t];
        d[4 * k + 0] = d4.x; d[4 * k + 1] = d4.y; d[4 * k + 2] = d4.z; d[4 * k + 3] = d4.w;
        s[4 * k + 0] = s4.x; s[4 * k + 1] = s4.y; s[4 * k + 2] = s4.z; s[4 * k + 3] = s4.w;
        atomicAdd(&h[d4.x >> 8], 1u);
        atomicAdd(&h[d4.y >> 8], 1u);
        atomicAdd(&h[d4.z >> 8], 1u);
        atomicAdd(&h[d4.w >> 8], 1u);
    }
    __syncthreads();
    uint v = h[t];
    uint sv = v;                                  // wave-level inclusive scan
#pragma unroll
    for (int off = 1; off < 64; off <<= 1) {
        uint n = __shfl_up(sv, off);
        if (lane >= off) sv += n;
    }
    if (lane == 63) wsum[w] = sv;
    __syncthreads();
    uint wo = 0;
    for (int i = 0; i < w; ++i) wo += wsum[i];
    sv += wo;                                     // inclusive over 512 buckets
    uint ex = sv - v;                             // local exclusive offset
    cnt16[(size_t)t * NBLK + g] = (u16)v;         // directory (bucket t, block g)
    dir16[(size_t)t * NBLK + g] = (u16)ex;
    __syncthreads();                              // all reads of h done
    h[t] = ex;                                    // bump starts at excl
    __syncthreads();
#pragma unroll
    for (int k = 0; k < EPT; ++k) {
        int b = d[k] >> 8;
        uint slot = atomicAdd(&h[b], 1u);
        vals[slot] = ((uint)s[k] << 8) | (uint)(d[k] & 255);
    }
    __syncthreads();
    uint4* part4 = (uint4*)(part + (size_t)g * CHUNK);
    const uint4* vals4 = (const uint4*)vals;
#pragma unroll
    for (int k = 0; k < EPT / 4; ++k)             // fully coalesced 16B stores
        part4[k * SCT + t] = vals4[k * SCT + t];
}

// ---- Phase B: per-bucket gather (via directory) + node-level sort ----------
// Output layout: part2[b*CAPB + i] (padded, no global scan needed);
// csr/cend per node; dinv; y = dinv*x.
__global__ void __launch_bounds__(SCT) k_sort(
        const uint* __restrict__ part, const u16* __restrict__ cnt16,
        const u16* __restrict__ dir16, const float* __restrict__ x,
        uint* __restrict__ part2, uint* __restrict__ csr, uint* __restrict__ cend,
        float* __restrict__ dinv, float2* __restrict__ y) {
    __shared__ uint hw[8 * 256];   // wave-private bin counters (8 KB)
    __shared__ uint cnt[256];      // per-node-bin totals
    __shared__ uint sc[256];       // inclusive scan of totals
    __shared__ uint wsum[4];
    __shared__ uint srt[CAPB];     // 36 KB
    int t = threadIdx.x, b = blockIdx.x;
    int lane = t & 63, w = t >> 6;
#pragma unroll
    for (int k = 0; k < 4; ++k) hw[k * SCT + t] = 0;
    __syncthreads();
    // thread t owns the segment this bucket has inside block g=t
    uint segc = cnt16[(size_t)b * NBLK + t];
    const uint* seg = part + (size_t)t * CHUNK + dir16[(size_t)b * NBLK + t];
    for (uint j = 0; j < segc; ++j)               // pass 1: count node bins
        atomicAdd(&hw[w * 256 + (seg[j] & 255u)], 1u);
    __syncthreads();
    if (t < 256) {                                // wave-exclusive transform
        uint tot = 0;
#pragma unroll
        for (int k = 0; k < 8; ++k) {
            uint c = hw[k * 256 + t];
            hw[k * 256 + t] = tot;
            tot += c;
        }
        cnt[t] = tot;
        uint sv = tot;                            // shfl inclusive scan, 4 waves
#pragma unroll
        for (int off = 1; off < 64; off <<= 1) {
            uint n = __shfl_up(sv, off);
            if (lane >= off) sv += n;
        }
        if (lane == 63) wsum[t >> 6] = sv;
        sc[t] = sv;                               // partial (pre cross-wave)
    }
    __syncthreads();
    if (t < 256) {
        uint wo = 0;
        for (int i = 0; i < (t >> 6); ++i) wo += wsum[i];
        sc[t] += wo;                              // inclusive over 256 bins
    }
    __syncthreads();
    for (uint j = 0; j < segc; ++j) {             // pass 2: place (L1/L2-hot)
        uint pk = seg[j];
        uint bin = pk & 255u;
        uint slot = (sc[bin] - cnt[bin]) + atomicAdd(&hw[w * 256 + bin], 1u);
        if (slot < (uint)CAPB) srt[slot] = pk >> 8;
    }
    __syncthreads();
    uint L = sc[255];
    if (L > (uint)CAPB) L = CAPB;
    uint* out2 = part2 + (size_t)b * CAPB;
    for (uint i = t; i < L; i += SCT) out2[i] = srt[i];   // coalesced flush
    if (t < 256) {
        int node = (b << 8) + t;
        uint o0 = sc[t] - cnt[t];
        csr[node]  = (uint)b * CAPB + o0;
        cend[node] = (uint)b * CAPB + sc[t];
        float di = rsqrtf(1.0f + (float)cnt[t]);  // +1 self-loop
        dinv[node] = di;
        float2 xv = ((const float2*)x)[node];
        y[node] = make_float2(di * xv.x, di * xv.y);
    }
}

// ---- layer 1: CSR reduction (16 lanes/node) + one-feature-per-lane MLP -----
__global__ void k_l1(const uint* __restrict__ srcs, const uint* __restrict__ csr,
                     const uint* __restrict__ cend,
                     const float2* __restrict__ y, const float* __restrict__ dinv,
                     const float* __restrict__ W1, const float* __restrict__ b1,
                     const float* __restrict__ W2, float* __restrict__ g2) {
    int tid = blockIdx.x * blockDim.x + threadIdx.x;
    int node = tid >> 4, lane = tid & (LPN - 1);
    uint o0 = csr[node];
    uint o1 = cend[node];
    float A0 = 0.0f, A1 = 0.0f;
    for (uint j = o0 + lane; j < o1; j += LPN) {
        float2 ys = y[srcs[j]];
        A0 += ys.x; A1 += ys.y;
    }
    A0 += __shfl_xor(A0, 1); A0 += __shfl_xor(A0, 2);
    A0 += __shfl_xor(A0, 4); A0 += __shfl_xor(A0, 8);
    A1 += __shfl_xor(A1, 1); A1 += __shfl_xor(A1, 2);
    A1 += __shfl_xor(A1, 4); A1 += __shfl_xor(A1, 8);
    float di = dinv[node];
    float2 yn = y[node];
    A0 = di * (A0 + yn.x);                              // + self-loop, * dinv[d]
    A1 = di * (A1 + yn.y);
    int f = lane;                                       // one feature per lane
    float v = fmaf(A0, W1[f], fmaf(A1, W1[F + f], b1[f]));
    float acc = fmaxf(v, 0.0f) * W2[f];
    acc += __shfl_xor(acc, 1); acc += __shfl_xor(acc, 2);
    acc += __shfl_xor(acc, 4); acc += __shfl_xor(acc, 8);
    if (lane == 0) g2[node] = di * acc;
}

// ---- layer 2: CSR reduction (16 lanes/node) + sigmoid -> scores ------------
__global__ void k_l2(const uint* __restrict__ srcs, const uint* __restrict__ csr,
                     const uint* __restrict__ cend,
                     const float* __restrict__ g2, const float* __restrict__ dinv,
                     const float* __restrict__ b2, float* __restrict__ scores) {
    int tid = blockIdx.x * blockDim.x + threadIdx.x;
    int node = tid >> 4, lane = tid & (LPN - 1);
    uint o0 = csr[node];
    uint o1 = cend[node];
    float acc = 0.0f;
    for (uint j = o0 + lane; j < o1; j += LPN) acc += g2[srcs[j]];
    acc += __shfl_xor(acc, 1); acc += __shfl_xor(acc, 2);
    acc += __shfl_xor(acc, 4); acc += __shfl_xor(acc, 8);
    if (lane == 0) {
        float v = fmaf(dinv[node], acc + g2[node], b2[0]);
        scores[node] = 1.0f / (1.0f + expf(-v));
    }
}

// ---- output gather: out[e] = scores[src[e]], 4 edges/thread ----------------
__global__ void k_out(const int* __restrict__ src, const float* __restrict__ scores,
                      float* __restrict__ out) {
    int i = blockIdx.x * blockDim.x + threadIdx.x;
    if (i >= E / 4) return;
    int4 s4 = ((const int4*)src)[i];
    float4 o;
    o.x = scores[s4.x];
    o.y = scores[s4.y];
    o.z = scores[s4.z];
    o.w = scores[s4.w];
    ((float4*)out)[i] = o;
}

extern "C" void kernel_launch(void* const* d_in, const int* in_sizes, int n_in,
                              void* d_out, int out_size, void* d_ws, size_t ws_size,
                              hipStream_t stream) {
    const float* x  = (const float*)d_in[0];   // [N,2]
    const float* W1 = (const float*)d_in[1];   // [2,16]
    const float* b1 = (const float*)d_in[2];   // [16]
    const float* W2 = (const float*)d_in[3];   // [16,1]
    const float* b2 = (const float*)d_in[4];   // [1]
    const int*   ei = (const int*)d_in[5];     // [2,E]
    const int* src = ei;
    const int* dst = ei + E;

    // ws: cnt16[256K u16] | dir16[256K u16] | csr[N] | cend[N] | dinv[N] |
    //     y[N f32x2] | g2[N] | scores[N] | part2[512*CAPB u32]   (~23.5 MB)
    u16* cnt16   = (u16*)d_ws;
    u16* dir16   = cnt16 + (size_t)NB * NBLK;
    uint* csr    = (uint*)(dir16 + (size_t)NB * NBLK);
    uint* cend   = csr + N;
    float* dinv  = (float*)(cend + N);
    float2* y    = (float2*)(dinv + N);
    float* g2    = (float*)(y + N);
    float* scores = g2 + N;
    uint* part2  = (uint*)(scores + N);

    // block-grouped edges (16 MB) live in d_out; dead before k_out writes
    uint* part  = (uint*)d_out;
    float* out  = (float*)d_out;

    k_scatter<<<NBLK,            SCT, 0, stream>>>(src, dst, part, cnt16, dir16);
    k_sort   <<<NB,              SCT, 0, stream>>>(part, cnt16, dir16, x, part2,
                                                   csr, cend, dinv, y);
    k_l1     <<<(N * LPN) / 256, 256, 0, stream>>>(part2, csr, cend, y, dinv,
                                                   W1, b1, W2, g2);
    k_l2     <<<(N * LPN) / 256, 256, 0, stream>>>(part2, csr, cend, g2, dinv,
                                                   b2, scores);
    k_out    <<<E / 4 / 256,     256, 0, stream>>>(src, scores, out);
}